// Round 2
// baseline (1601.676 us; speedup 1.0000x reference)
//
#include <hip/hip_runtime.h>

#define NGRAPH 100
#define NPER   1000
#define NNODES 100000
#define NEDGES 1600000
#define EPG    16000   // edges per graph
#define NB     4

// ==================== sort edges by src (counting sort per graph) ==========
__global__ __launch_bounds__(256) void zero_int_k(int* __restrict__ p, int n) {
    int i = blockIdx.x * 256 + threadIdx.x;
    if (i < n) p[i] = 0;
}

__global__ __launch_bounds__(256) void hist_k(const int* __restrict__ src,
                                              int* __restrict__ count) {
    int e = blockIdx.x * 256 + threadIdx.x;
    if (e < NEDGES) atomicAdd(&count[src[e]], 1);
}

__global__ __launch_bounds__(1024) void scan_k(const int* __restrict__ count,
                                               int* __restrict__ offs) {
    __shared__ int sc[1024];
    int t = threadIdx.x, g = blockIdx.x;
    int v = (t < NPER) ? count[g * NPER + t] : 0;
    sc[t] = v;
    __syncthreads();
    for (int s = 1; s < 1024; s <<= 1) {
        int add = (t >= s) ? sc[t - s] : 0;
        __syncthreads();
        sc[t] += add;
        __syncthreads();
    }
    if (t < NPER) offs[g * NPER + t] = g * EPG + sc[t] - v;  // exclusive
}

__global__ __launch_bounds__(256) void scatter_k(
    const int* __restrict__ src, const int* __restrict__ dst,
    const int* __restrict__ et, const int* __restrict__ el,
    int* __restrict__ offs, int4* __restrict__ sorted) {
    int e = blockIdx.x * 256 + threadIdx.x;
    if (e >= NEDGES) return;
    int s = src[e];
    int p = atomicAdd(&offs[s], 1);
    sorted[p] = make_int4(s, dst[e], et[e], el[e]);
}

// ==================== per-layer node projections ===========================
// xproj[n][o][b] = sum_d h[n,d]*basis[l,b,d,o]   (b-minor packed layout!)
// psrc[n,o] = h·A_w[0:32], pdst[n,o] = h·A_w[32:64], nei[n,o] = h·self_loop_w
__device__ __forceinline__ float4 dot32x4(const float* __restrict__ w,
                                          const float* hreg, int oc) {
    float4 a = {0.f, 0.f, 0.f, 0.f};
    #pragma unroll
    for (int d = 0; d < 32; d++) {
        float4 wv = *(const float4*)(w + d * 32 + oc * 4);
        a.x = fmaf(hreg[d], wv.x, a.x);
        a.y = fmaf(hreg[d], wv.y, a.y);
        a.z = fmaf(hreg[d], wv.z, a.z);
        a.w = fmaf(hreg[d], wv.w, a.w);
    }
    return a;
}

__global__ __launch_bounds__(256) void node_project_k(
    const float* __restrict__ h, const float* __restrict__ basis_l,
    const float* __restrict__ selfw_l, const float* __restrict__ Aw_l,
    float* __restrict__ xproj, float* __restrict__ psrc,
    float* __restrict__ pdst, float* __restrict__ nei)
{
    __shared__ float w_s[7168]; // [0,4096) basis b0..b3, [4096,5120) selfw, [5120,6144) A1, [6144,7168) A2
    for (int k = threadIdx.x; k < 7168; k += 256) {
        float v;
        if (k < 4096)      v = basis_l[k];
        else if (k < 5120) v = selfw_l[k - 4096];
        else               v = Aw_l[k - 5120];
        w_s[k] = v;
    }
    __syncthreads();
    int n = blockIdx.x * 256 + threadIdx.x;
    if (n >= NNODES) return;

    float hreg[32];
    const float4* hp = (const float4*)(h + (size_t)n * 32);
    #pragma unroll
    for (int k = 0; k < 8; k++) {
        float4 v = hp[k];
        hreg[4*k+0]=v.x; hreg[4*k+1]=v.y; hreg[4*k+2]=v.z; hreg[4*k+3]=v.w;
    }

    float* xout = xproj + (size_t)n * 128;
    #pragma unroll 1
    for (int oc = 0; oc < 8; oc++) {
        float4 b0 = dot32x4(w_s + 0,    hreg, oc);
        float4 b1 = dot32x4(w_s + 1024, hreg, oc);
        float4 b2 = dot32x4(w_s + 2048, hreg, oc);
        float4 b3 = dot32x4(w_s + 3072, hreg, oc);
        // transpose: xout[(oc*4+j)*4 + b]
        float4 t0 = {b0.x, b1.x, b2.x, b3.x};
        float4 t1 = {b0.y, b1.y, b2.y, b3.y};
        float4 t2 = {b0.z, b1.z, b2.z, b3.z};
        float4 t3 = {b0.w, b1.w, b2.w, b3.w};
        *(float4*)(xout + (oc*4+0)*4) = t0;
        *(float4*)(xout + (oc*4+1)*4) = t1;
        *(float4*)(xout + (oc*4+2)*4) = t2;
        *(float4*)(xout + (oc*4+3)*4) = t3;
        *(float4*)(nei  + (size_t)n*32 + oc*4) = dot32x4(w_s + 4096, hreg, oc);
        *(float4*)(psrc + (size_t)n*32 + oc*4) = dot32x4(w_s + 5120, hreg, oc);
        *(float4*)(pdst + (size_t)n*32 + oc*4) = dot32x4(w_s + 6144, hreg, oc);
    }
}

// ==================== per-relation attention tables ========================
__global__ __launch_bounds__(64) void rel_tables_k(
    const float* __restrict__ attn_tab, const float* __restrict__ Aw_l,
    const float* __restrict__ Ab_l, float* __restrict__ t1, float* __restrict__ t2)
{
    int r = blockIdx.x;
    int t = threadIdx.x;
    int o = t & 31;
    bool second = t >= 32;
    const float* at = attn_tab + r * 32;
    const float* W  = Aw_l + (second ? 96*32 : 64*32);
    float acc = second ? 0.f : Ab_l[o];
    #pragma unroll
    for (int d = 0; d < 32; d++) acc += at[d] * W[d*32 + o];
    (second ? t2 : t1)[r*32 + o] = acc;
}

// ==================== edge kernel: LDS per-graph accumulator ===============
// 2 blocks per graph, each handles 8000 sorted edges; full 1000x32 acc in LDS.
__global__ __launch_bounds__(1024) void edge_lds_k(
    const int4* __restrict__ sorted,
    const float* __restrict__ psrc, const float* __restrict__ pdst,
    const float* __restrict__ t1,   const float* __restrict__ t2,
    const float* __restrict__ xproj, const float* __restrict__ wcomp_l,
    const float* __restrict__ Bw, const float* __restrict__ Bb,
    float* __restrict__ nei)
{
    __shared__ float acc_s[NPER * 32];   // 128 000 B
    for (int k = threadIdx.x; k < NPER * 32; k += 1024) acc_s[k] = 0.f;
    __syncthreads();

    const int g    = blockIdx.x >> 1;
    const int half = blockIdx.x & 1;
    const int base = g * EPG + half * (EPG / 2);
    const int i    = threadIdx.x & 31;   // channel
    const int grp  = threadIdx.x >> 5;   // 0..31 edge groups
    const float bw = Bw[i];
    const float bb = Bb[0];
    const int nbase = g * NPER;

    #pragma unroll 1
    for (int it = 0; it < (EPG/2)/32; it++) {   // 250 iters
        int e = base + it * 32 + grp;
        int4 ed = sorted[e];
        int s_ = ed.x, d_ = ed.y, et_ = ed.z, el_ = ed.w;
        float z = psrc[(size_t)s_*32 + i] + pdst[(size_t)d_*32 + i]
                + t1[et_*32 + i] + t2[el_*32 + i];
        z = fmaxf(z, 0.f);
        float part = z * bw;
        part += __shfl_xor(part, 1, 32);
        part += __shfl_xor(part, 2, 32);
        part += __shfl_xor(part, 4, 32);
        part += __shfl_xor(part, 8, 32);
        part += __shfl_xor(part, 16, 32);
        float a = 1.f / (1.f + __expf(-(part + bb)));
        float4 c  = *(const float4*)(wcomp_l + et_*4);
        float4 xv = *(const float4*)(xproj + (size_t)s_*128 + i*4);
        float msg = c.x*xv.x + c.y*xv.y + c.z*xv.z + c.w*xv.w;
        atomicAdd(&acc_s[(d_ - nbase)*32 + i], a * msg);
    }
    __syncthreads();
    float* ng = nei + (size_t)nbase * 32;
    for (int k = threadIdx.x; k < NPER * 32; k += 1024)
        atomicAdd(&ng[k], acc_s[k]);
}

// ==================== relu + exact per-graph mean ==========================
__global__ __launch_bounds__(256) void finish_k(
    const float* __restrict__ nei, float* __restrict__ h_next,
    float* __restrict__ g_acc, int l)
{
    int g   = blockIdx.x;
    int sub = threadIdx.x >> 5;
    int i   = threadIdx.x & 31;
    float acc = 0.f;
    #pragma unroll 1
    for (int k = 0; k < NPER/8; k++) {
        int n = g*NPER + sub + k*8;
        float v = fmaxf(nei[(size_t)n*32 + i], 0.f);
        h_next[(size_t)n*32 + i] = v;
        acc += v;
    }
    __shared__ float red[8][32];
    red[sub][i] = acc;
    __syncthreads();
    if (threadIdx.x < 32) {
        float s2 = 0.f;
        #pragma unroll
        for (int k = 0; k < 8; k++) s2 += red[k][threadIdx.x];
        g_acc[g*96 + l*32 + threadIdx.x] = s2 * (1.0f/NPER);
    }
}

__global__ __launch_bounds__(256) void headtail_k(
    const float* __restrict__ h, const int* __restrict__ head_ids,
    const int* __restrict__ tail_ids, float* __restrict__ head_buf,
    float* __restrict__ tail_buf, int l)
{
    int idx = blockIdx.x * 256 + threadIdx.x;
    if (idx >= NGRAPH * 32) return;
    int g = idx >> 5;
    int i = idx & 31;
    head_buf[g*96 + l*32 + i] = h[(size_t)head_ids[g]*32 + i];
    tail_buf[g*96 + l*32 + i] = h[(size_t)tail_ids[g]*32 + i];
}

__global__ __launch_bounds__(64) void readout_k(
    const float* __restrict__ g_acc, const float* __restrict__ head_buf,
    const float* __restrict__ tail_buf, const float* __restrict__ rel_tab,
    const int* __restrict__ rel_labels, const float* __restrict__ fc_w,
    const float* __restrict__ fc_b, float* __restrict__ out)
{
    int g = blockIdx.x;
    int t = threadIdx.x;
    float s = 0.f;
    for (int idx = t; idx < 320; idx += 64) {
        float v;
        if (idx < 96)       v = g_acc[g*96 + idx];
        else if (idx < 192) v = head_buf[g*96 + idx - 96];
        else if (idx < 288) v = tail_buf[g*96 + idx - 192];
        else                v = rel_tab[rel_labels[g]*32 + (idx - 288)];
        s += v * fc_w[idx];
    }
    s += __shfl_xor(s, 1, 64);
    s += __shfl_xor(s, 2, 64);
    s += __shfl_xor(s, 4, 64);
    s += __shfl_xor(s, 8, 64);
    s += __shfl_xor(s, 16, 64);
    s += __shfl_xor(s, 32, 64);
    if (t == 0) out[g] = s + fc_b[0];
}

extern "C" void kernel_launch(void* const* d_in, const int* in_sizes, int n_in,
                              void* d_out, int out_size, void* d_ws, size_t ws_size,
                              hipStream_t stream) {
    const float* feat        = (const float*)d_in[0];
    const float* basis       = (const float*)d_in[1];   // [3,4,32,32]
    const float* w_comp      = (const float*)d_in[2];   // [3,200,4]
    const float* self_loop_w = (const float*)d_in[3];   // [3,32,32]
    const float* A_w         = (const float*)d_in[4];   // [3,128,32]
    const float* A_b         = (const float*)d_in[5];   // [3,32]
    const float* B_w         = (const float*)d_in[6];   // [3,32,1]
    const float* B_b         = (const float*)d_in[7];   // [3,1]
    const float* attn_tab    = (const float*)d_in[8];   // [200,32]
    const float* rel_tab     = (const float*)d_in[9];   // [200,32]
    const float* fc_w        = (const float*)d_in[10];  // [320,1]
    const float* fc_b        = (const float*)d_in[11];  // [1]
    const int* src        = (const int*)d_in[12];
    const int* dst        = (const int*)d_in[13];
    const int* etype      = (const int*)d_in[14];
    const int* elabel     = (const int*)d_in[15];
    const int* head_ids   = (const int*)d_in[17];
    const int* tail_ids   = (const int*)d_in[18];
    const int* rel_labels = (const int*)d_in[19];

    float* ws = (float*)d_ws;
    size_t off = 0;
    float* h0    = ws + off; off += (size_t)NNODES * 32;
    float* h1    = ws + off; off += (size_t)NNODES * 32;
    float* xproj = ws + off; off += (size_t)NNODES * 128;
    float* psrc  = ws + off; off += (size_t)NNODES * 32;
    float* pdst  = ws + off; off += (size_t)NNODES * 32;
    float* nei   = ws + off; off += (size_t)NNODES * 32;
    float* t1    = ws + off; off += 200 * 32;
    float* t2    = ws + off; off += 200 * 32;
    float* g_acc    = ws + off; off += NGRAPH * 96;
    float* head_buf = ws + off; off += NGRAPH * 96;
    float* tail_buf = ws + off; off += NGRAPH * 96;
    int* count = (int*)(ws + off); off += NNODES;
    int* offs  = (int*)(ws + off); off += NNODES;
    off = (off + 3) & ~(size_t)3;               // align 16 B
    int4* sorted = (int4*)(ws + off); off += (size_t)NEDGES * 4;

    // ---- one-time edge sort by src (reused for all 3 layers) ----
    zero_int_k<<<(NNODES + 255)/256, 256, 0, stream>>>(count, NNODES);
    hist_k<<<(NEDGES + 255)/256, 256, 0, stream>>>(src, count);
    scan_k<<<NGRAPH, 1024, 0, stream>>>(count, offs);
    scatter_k<<<(NEDGES + 255)/256, 256, 0, stream>>>(src, dst, etype, elabel,
                                                      offs, sorted);

    const float* hcur = feat;
    float* hbufs[2] = { h0, h1 };
    for (int l = 0; l < 3; l++) {
        node_project_k<<<(NNODES + 255)/256, 256, 0, stream>>>(
            hcur, basis + (size_t)l*4096, self_loop_w + (size_t)l*1024,
            A_w + (size_t)l*4096, xproj, psrc, pdst, nei);
        rel_tables_k<<<200, 64, 0, stream>>>(
            attn_tab, A_w + (size_t)l*4096, A_b + (size_t)l*32, t1, t2);
        edge_lds_k<<<NGRAPH*2, 1024, 0, stream>>>(
            sorted, psrc, pdst, t1, t2, xproj,
            w_comp + (size_t)l*800, B_w + (size_t)l*32, B_b + l, nei);
        float* hn = hbufs[l & 1];
        finish_k<<<NGRAPH, 256, 0, stream>>>(nei, hn, g_acc, l);
        headtail_k<<<(NGRAPH*32 + 255)/256, 256, 0, stream>>>(
            hn, head_ids, tail_ids, head_buf, tail_buf, l);
        hcur = hn;
    }
    readout_k<<<NGRAPH, 64, 0, stream>>>(
        g_acc, head_buf, tail_buf, rel_tab, rel_labels, fc_w, fc_b, (float*)d_out);
}

// Round 3
// 766.959 us; speedup vs baseline: 2.0883x; 2.0883x over previous
//
#include <hip/hip_runtime.h>

#define NGRAPH 100
#define NPER   1000
#define NNODES 100000
#define NEDGES 1600000
#define EPG    16000   // edges per graph

// ==================== small utility kernels ====================
__global__ __launch_bounds__(256) void zero_int_k(int* __restrict__ p, int n) {
    int i = blockIdx.x * 256 + threadIdx.x;
    if (i < n) p[i] = 0;
}
__global__ __launch_bounds__(256) void zero_float_k(float* __restrict__ p, int n) {
    int i = blockIdx.x * 256 + threadIdx.x;
    if (i < n) p[i] = 0.f;
}

// ==================== counting sort of edges by DST ====================
__global__ __launch_bounds__(256) void hist_k(const int* __restrict__ dst,
                                              int* __restrict__ count) {
    int e = blockIdx.x * 256 + threadIdx.x;
    if (e < NEDGES) atomicAdd(&count[dst[e]], 1);
}

// per-graph exclusive scan -> offs (kept) and cursor (mutated by scatter)
__global__ __launch_bounds__(1024) void scan_k(const int* __restrict__ count,
                                               int* __restrict__ offs,
                                               int* __restrict__ cursor) {
    __shared__ int sc[1024];
    int t = threadIdx.x, g = blockIdx.x;
    int v = (t < NPER) ? count[g * NPER + t] : 0;
    sc[t] = v;
    __syncthreads();
    for (int s = 1; s < 1024; s <<= 1) {
        int add = (t >= s) ? sc[t - s] : 0;
        __syncthreads();
        sc[t] += add;
        __syncthreads();
    }
    if (t < NPER) {
        int start = g * EPG + sc[t] - v;   // exclusive
        offs[g * NPER + t]   = start;
        cursor[g * NPER + t] = start;
    }
}

__global__ __launch_bounds__(256) void scatter_k(
    const int* __restrict__ src, const int* __restrict__ dst,
    const int* __restrict__ et, const int* __restrict__ el,
    int* __restrict__ cursor, int4* __restrict__ sorted) {
    int e = blockIdx.x * 256 + threadIdx.x;
    if (e >= NEDGES) return;
    int d = dst[e];
    int p = atomicAdd(&cursor[d], 1);
    sorted[p] = make_int4(src[e], et[e], el[e], 0);
}

// ==================== node projections, 4 output-slices ====================
// y=0: xproj b0,b1   y=1: xproj b2,b3   y=2: psrc,pdst   y=3: selfp
// xproj packed b-minor: xproj[n][o][b]  (float4 per (n,o))
__device__ __forceinline__ float4 dot32x4(const float* __restrict__ w,
                                          const float* hreg, int oc) {
    float4 a = {0.f, 0.f, 0.f, 0.f};
    #pragma unroll
    for (int d = 0; d < 32; d++) {
        float4 wv = *(const float4*)(w + d * 32 + oc * 4);
        a.x = fmaf(hreg[d], wv.x, a.x);
        a.y = fmaf(hreg[d], wv.y, a.y);
        a.z = fmaf(hreg[d], wv.z, a.z);
        a.w = fmaf(hreg[d], wv.w, a.w);
    }
    return a;
}

__global__ __launch_bounds__(256) void node_slice_k(
    const float* __restrict__ h, const float* __restrict__ basis_l,
    const float* __restrict__ selfw_l, const float* __restrict__ Aw_l,
    float* __restrict__ xproj, float* __restrict__ psrc,
    float* __restrict__ pdst, float* __restrict__ selfp)
{
    const int y = blockIdx.y;
    __shared__ float w_s[2048];
    const float* srcw;
    int cnt;
    if (y == 0)      { srcw = basis_l;        cnt = 2048; }
    else if (y == 1) { srcw = basis_l + 2048; cnt = 2048; }
    else if (y == 2) { srcw = Aw_l;           cnt = 2048; }  // A rows 0..63
    else             { srcw = selfw_l;        cnt = 1024; }
    for (int k = threadIdx.x; k < cnt; k += 256) w_s[k] = srcw[k];
    __syncthreads();

    int n = blockIdx.x * 256 + threadIdx.x;
    if (n >= NNODES) return;

    float hreg[32];
    const float4* hp = (const float4*)(h + (size_t)n * 32);
    #pragma unroll
    for (int k = 0; k < 8; k++) {
        float4 v = hp[k];
        hreg[4*k+0]=v.x; hreg[4*k+1]=v.y; hreg[4*k+2]=v.z; hreg[4*k+3]=v.w;
    }

    if (y < 2) {
        float* xout = xproj + (size_t)n * 128 + 2 * y;
        #pragma unroll 1
        for (int oc = 0; oc < 8; oc++) {
            float4 p = dot32x4(w_s,        hreg, oc);  // basis lo
            float4 q = dot32x4(w_s + 1024, hreg, oc);  // basis hi
            *(float2*)(xout + (oc*4+0)*4) = make_float2(p.x, q.x);
            *(float2*)(xout + (oc*4+1)*4) = make_float2(p.y, q.y);
            *(float2*)(xout + (oc*4+2)*4) = make_float2(p.z, q.z);
            *(float2*)(xout + (oc*4+3)*4) = make_float2(p.w, q.w);
        }
    } else if (y == 2) {
        #pragma unroll 1
        for (int oc = 0; oc < 8; oc++) {
            *(float4*)(psrc + (size_t)n*32 + oc*4) = dot32x4(w_s,        hreg, oc);
            *(float4*)(pdst + (size_t)n*32 + oc*4) = dot32x4(w_s + 1024, hreg, oc);
        }
    } else {
        #pragma unroll 1
        for (int oc = 0; oc < 8; oc++)
            *(float4*)(selfp + (size_t)n*32 + oc*4) = dot32x4(w_s, hreg, oc);
    }
}

// ==================== per-relation attention tables ====================
__global__ __launch_bounds__(64) void rel_tables_k(
    const float* __restrict__ attn_tab, const float* __restrict__ Aw_l,
    const float* __restrict__ Ab_l, float* __restrict__ t1, float* __restrict__ t2)
{
    int r = blockIdx.x;
    int t = threadIdx.x;
    int o = t & 31;
    bool second = t >= 32;
    const float* at = attn_tab + r * 32;
    const float* W  = Aw_l + (second ? 96*32 : 64*32);
    float acc = second ? 0.f : Ab_l[o];
    #pragma unroll
    for (int d = 0; d < 32; d++) acc += at[d] * W[d*32 + o];
    (second ? t2 : t1)[r*32 + o] = acc;
}

// ==================== CSR edge kernel: 32 lanes per dst node ====================
// Computes nei-sum in registers, fuses self-loop + relu + h_next write +
// per-graph mean contribution. No global accumulator buffer, no big atomics.
__global__ __launch_bounds__(256) void edge_csr_k(
    const int4* __restrict__ sorted, const int* __restrict__ offs,
    const float* __restrict__ psrc, const float* __restrict__ pdst,
    const float* __restrict__ t1,   const float* __restrict__ t2,
    const float* __restrict__ xproj, const float* __restrict__ selfp,
    const float* __restrict__ wcomp_l,
    const float* __restrict__ Bw, const float* __restrict__ Bb,
    float* __restrict__ h_next, float* __restrict__ g_acc, int l)
{
    const int grp = threadIdx.x >> 5;          // 0..7  (node within block)
    const int i   = threadIdx.x & 31;          // channel
    const int g   = blockIdx.x / 125;          // 125 blocks per graph (1000/8)
    const int n   = g * NPER + (blockIdx.x % 125) * 8 + grp;

    const int start = offs[n];
    const int end   = (n == NNODES - 1) ? NEDGES : offs[n + 1];
    const float bw = Bw[i];
    const float bb = Bb[0];
    const float pd = pdst[(size_t)n * 32 + i];

    float acc = 0.f;
    for (int e = start; e < end; e++) {
        int4 ed = sorted[e];
        int s_ = ed.x, et_ = ed.y, el_ = ed.z;
        float z = psrc[(size_t)s_*32 + i] + pd + t1[et_*32 + i] + t2[el_*32 + i];
        z = fmaxf(z, 0.f);
        float part = z * bw;
        part += __shfl_xor(part, 1, 32);
        part += __shfl_xor(part, 2, 32);
        part += __shfl_xor(part, 4, 32);
        part += __shfl_xor(part, 8, 32);
        part += __shfl_xor(part, 16, 32);
        float a = __builtin_amdgcn_rcpf(1.f + __expf(-(part + bb)));
        float4 c  = *(const float4*)(wcomp_l + et_ * 4);
        float4 xv = *(const float4*)(xproj + (size_t)s_ * 128 + i * 4);
        float msg = c.x*xv.x + c.y*xv.y + c.z*xv.z + c.w*xv.w;
        acc = fmaf(a, msg, acc);
    }

    float hv = fmaxf(acc + selfp[(size_t)n*32 + i], 0.f);
    h_next[(size_t)n*32 + i] = hv;

    // per-graph mean contribution (block is entirely within one graph)
    __shared__ float red[8][32];
    red[grp][i] = hv;
    __syncthreads();
    if (threadIdx.x < 32) {
        float s2 = 0.f;
        #pragma unroll
        for (int k = 0; k < 8; k++) s2 += red[k][threadIdx.x];
        atomicAdd(&g_acc[g*96 + l*32 + threadIdx.x], s2 * (1.0f / NPER));
    }
}

// ==================== head/tail gather ====================
__global__ __launch_bounds__(256) void headtail_k(
    const float* __restrict__ h, const int* __restrict__ head_ids,
    const int* __restrict__ tail_ids, float* __restrict__ head_buf,
    float* __restrict__ tail_buf, int l)
{
    int idx = blockIdx.x * 256 + threadIdx.x;
    if (idx >= NGRAPH * 32) return;
    int g = idx >> 5;
    int i = idx & 31;
    head_buf[g*96 + l*32 + i] = h[(size_t)head_ids[g]*32 + i];
    tail_buf[g*96 + l*32 + i] = h[(size_t)tail_ids[g]*32 + i];
}

// ==================== final readout ====================
__global__ __launch_bounds__(64) void readout_k(
    const float* __restrict__ g_acc, const float* __restrict__ head_buf,
    const float* __restrict__ tail_buf, const float* __restrict__ rel_tab,
    const int* __restrict__ rel_labels, const float* __restrict__ fc_w,
    const float* __restrict__ fc_b, float* __restrict__ out)
{
    int g = blockIdx.x;
    int t = threadIdx.x;
    float s = 0.f;
    for (int idx = t; idx < 320; idx += 64) {
        float v;
        if (idx < 96)       v = g_acc[g*96 + idx];
        else if (idx < 192) v = head_buf[g*96 + idx - 96];
        else if (idx < 288) v = tail_buf[g*96 + idx - 192];
        else                v = rel_tab[rel_labels[g]*32 + (idx - 288)];
        s += v * fc_w[idx];
    }
    s += __shfl_xor(s, 1, 64);
    s += __shfl_xor(s, 2, 64);
    s += __shfl_xor(s, 4, 64);
    s += __shfl_xor(s, 8, 64);
    s += __shfl_xor(s, 16, 64);
    s += __shfl_xor(s, 32, 64);
    if (t == 0) out[g] = s + fc_b[0];
}

extern "C" void kernel_launch(void* const* d_in, const int* in_sizes, int n_in,
                              void* d_out, int out_size, void* d_ws, size_t ws_size,
                              hipStream_t stream) {
    const float* feat        = (const float*)d_in[0];
    const float* basis       = (const float*)d_in[1];   // [3,4,32,32]
    const float* w_comp      = (const float*)d_in[2];   // [3,200,4]
    const float* self_loop_w = (const float*)d_in[3];   // [3,32,32]
    const float* A_w         = (const float*)d_in[4];   // [3,128,32]
    const float* A_b         = (const float*)d_in[5];   // [3,32]
    const float* B_w         = (const float*)d_in[6];   // [3,32,1]
    const float* B_b         = (const float*)d_in[7];   // [3,1]
    const float* attn_tab    = (const float*)d_in[8];   // [200,32]
    const float* rel_tab     = (const float*)d_in[9];   // [200,32]
    const float* fc_w        = (const float*)d_in[10];  // [320,1]
    const float* fc_b        = (const float*)d_in[11];  // [1]
    const int* src        = (const int*)d_in[12];
    const int* dst        = (const int*)d_in[13];
    const int* etype      = (const int*)d_in[14];
    const int* elabel     = (const int*)d_in[15];
    const int* head_ids   = (const int*)d_in[17];
    const int* tail_ids   = (const int*)d_in[18];
    const int* rel_labels = (const int*)d_in[19];

    float* ws = (float*)d_ws;
    size_t off = 0;
    float* h0    = ws + off; off += (size_t)NNODES * 32;
    float* h1    = ws + off; off += (size_t)NNODES * 32;
    float* xproj = ws + off; off += (size_t)NNODES * 128;
    float* psrc  = ws + off; off += (size_t)NNODES * 32;
    float* pdst  = ws + off; off += (size_t)NNODES * 32;
    float* selfp = ws + off; off += (size_t)NNODES * 32;
    float* t1    = ws + off; off += 200 * 32;
    float* t2    = ws + off; off += 200 * 32;
    float* g_acc    = ws + off; off += NGRAPH * 96;
    float* head_buf = ws + off; off += NGRAPH * 96;
    float* tail_buf = ws + off; off += NGRAPH * 96;
    int* count  = (int*)(ws + off); off += NNODES;
    int* offs   = (int*)(ws + off); off += NNODES;
    int* cursor = (int*)(ws + off); off += NNODES;
    off = (off + 3) & ~(size_t)3;               // 16 B align
    int4* sorted = (int4*)(ws + off); off += (size_t)NEDGES * 4;

    // ---- one-time per call: CSR by dst + zero the mean accumulator ----
    zero_int_k<<<(NNODES + 255)/256, 256, 0, stream>>>(count, NNODES);
    zero_float_k<<<(NGRAPH*96 + 255)/256, 256, 0, stream>>>(g_acc, NGRAPH*96);
    hist_k<<<(NEDGES + 255)/256, 256, 0, stream>>>(dst, count);
    scan_k<<<NGRAPH, 1024, 0, stream>>>(count, offs, cursor);
    scatter_k<<<(NEDGES + 255)/256, 256, 0, stream>>>(src, dst, etype, elabel,
                                                      cursor, sorted);

    const float* hcur = feat;
    float* hbufs[2] = { h0, h1 };
    for (int l = 0; l < 3; l++) {
        dim3 npgrid((NNODES + 255)/256, 4);
        node_slice_k<<<npgrid, 256, 0, stream>>>(
            hcur, basis + (size_t)l*4096, self_loop_w + (size_t)l*1024,
            A_w + (size_t)l*4096, xproj, psrc, pdst, selfp);
        rel_tables_k<<<200, 64, 0, stream>>>(
            attn_tab, A_w + (size_t)l*4096, A_b + (size_t)l*32, t1, t2);
        float* hn = hbufs[l & 1];
        edge_csr_k<<<NNODES/8, 256, 0, stream>>>(
            sorted, offs, psrc, pdst, t1, t2, xproj, selfp,
            w_comp + (size_t)l*800, B_w + (size_t)l*32, B_b + l,
            hn, g_acc, l);
        headtail_k<<<(NGRAPH*32 + 255)/256, 256, 0, stream>>>(
            hn, head_ids, tail_ids, head_buf, tail_buf, l);
        hcur = hn;
    }
    readout_k<<<NGRAPH, 64, 0, stream>>>(
        g_acc, head_buf, tail_buf, rel_tab, rel_labels, fc_w, fc_b, (float*)d_out);
}